// Round 1
// 542.135 us; speedup vs baseline: 1.0538x; 1.0538x over previous
//
#include <hip/hip_runtime.h>

#define FCn 64      // FC
#define LDP 68      // padded LDS row stride (floats)
#define TEB 64      // edges per block (pass 1)
#define GJK 576     // 9*64 floats of G per node
#define ABP 12      // padded A-row stride per node

__device__ __forceinline__ float silu_f(float x) { return x / (1.f + __expf(-x)); }

// ---------------- precompute: fold s, rad_w2/rad_b2, proj_w*, 0.25 into
// MT (224x64, transposed: MT[c][k]), cvec(224), b0s(128)
__global__ __launch_bounds__(256) void precomp_kernel(
    const float* __restrict__ exp_w, const float* __restrict__ exp_b,
    const float* __restrict__ rad_w2, const float* __restrict__ rad_b2,
    const float* __restrict__ proj_w0, const float* __restrict__ proj_b0,
    const float* __restrict__ proj_w1, const float* __restrict__ proj_w2,
    float* __restrict__ MT, float* __restrict__ cvec, float* __restrict__ b0s)
{
    const int r = blockIdx.x;   // 0..63 -> M row r; 64 -> cvec/b0s
    const int c = threadIdx.x;  // 0..255
    const float* wrow = (r < FCn) ? (rad_w2 + (long long)r * 384) : rad_b2;
    float acc = 0.f;
    if (c < 128) {
        for (int q = 0; q < 128; ++q)
            acc += wrow[q] * (exp_w[q] + exp_b[q]) * proj_w0[q * 128 + c];
    } else if (c < 192) {
        const int d = c - 128;
        for (int q = 0; q < 128; ++q)
            acc += wrow[128 + q] * (exp_w[q] + exp_b[q]) * proj_w1[q * 64 + d];
    } else if (c < 224) {
        const int d = c - 192;
        for (int q = 0; q < 128; ++q)
            acc += wrow[256 + q] * (exp_w[q] + exp_b[q]) * proj_w2[q * 32 + d];
    }
    acc *= 0.25f;  // 1/sqrt(AVG_AGG)
    if (r < FCn) {
        if (c < 224) MT[c * FCn + r] = acc;   // transposed: column-contiguous per T-col
    } else {
        cvec[c] = acc;
        if (c < 128) b0s[c] = 0.25f * proj_b0[c];
    }
}

// ---------------- CSR build
__global__ __launch_bounds__(256) void hist_kernel(const int* __restrict__ dst, int* __restrict__ cnt, int E)
{
    for (int e = blockIdx.x * 256 + threadIdx.x; e < E; e += gridDim.x * 256)
        atomicAdd(&cnt[dst[e]], 1);
}

__global__ __launch_bounds__(256) void scan_kernel(const int* __restrict__ cnt, int* __restrict__ off,
                                                   int* __restrict__ cur, int Nn, int Etot)
{
    __shared__ int part[256];
    __shared__ int spart[257];
    const int t = threadIdx.x;
    const int per = (Nn + 255) / 256;
    int s = 0;
    for (int i = 0; i < per; ++i) {
        const int idx = t * per + i;
        if (idx < Nn) s += cnt[idx];
    }
    part[t] = s;
    __syncthreads();
    if (t == 0) {
        int run = 0;
        spart[0] = 0;
        for (int i = 0; i < 256; ++i) { run += part[i]; spart[i + 1] = run; }
    }
    __syncthreads();
    int run = spart[t];
    for (int i = 0; i < per; ++i) {
        const int idx = t * per + i;
        if (idx < Nn) { off[idx] = run; cur[idx] = run; run += cnt[idx]; }
    }
    if (t == 0) off[Nn] = Etot;
}

__global__ __launch_bounds__(256) void scatter_kernel(const int* __restrict__ dst, int* __restrict__ cur,
                                                      int* __restrict__ eids, int E)
{
    for (int e = blockIdx.x * 256 + threadIdx.x; e < E; e += gridDim.x * 256) {
        const int pos = atomicAdd(&cur[dst[e]], 1);
        eids[pos] = e;
    }
}

// ---------------- pass 1: GEMM1 + LN + silu per edge, then segment-accumulate
//   G[n,j,k] = sum_{e->n} edge_attr[e,j] * Hs[e,k]   (9 x 64 per node)
//   Ab[n,j]  = sum_{e->n} edge_attr[e,j]
// Edges processed in dst-sorted order => contiguous segments => register
// accumulation with wave-uniform flush (atomicAdd) on dst change.
__global__ __launch_bounds__(256, 4) void accumG_kernel(
    const float* __restrict__ edge_attr,    // E x 9
    const float* __restrict__ edge_scalars, // E x 64
    const int*   __restrict__ eids,         // E (sorted pos -> edge id)
    const int*   __restrict__ edge_dst,     // E
    const float* __restrict__ rad_w1,       // 64 x 64
    const float* __restrict__ rad_b1,       // 64
    const float* __restrict__ rad_gamma,    // 64
    const float* __restrict__ rad_beta,     // 64
    float* __restrict__ G,                  // N x 576 (zero-initialized)
    float* __restrict__ Ab,                 // N x 12  (zero-initialized)
    int E)
{
    __shared__ float XT[FCn * LDP];   // [k][e] staging; reused as He [e][k] after LN
    __shared__ float Hb[TEB * LDP];   // [e][c] GEMM1 output
    __shared__ float Ea[TEB * ABP];   // [e][j] edge_attr
    __shared__ int   eids_l[TEB];
    __shared__ int   dst_l[TEB];
    const int t = threadIdx.x;
    const int p0 = blockIdx.x * TEB;

    if (t < TEB) {
        const int p = p0 + t;
        const int eid = (p < E) ? eids[p] : -1;
        eids_l[t] = eid;
        dst_l[t]  = (eid >= 0) ? edge_dst[eid] : -1;
    }
    __syncthreads();

    // ---- stage X^T (gathered 256B rows) + edge_attr
    #pragma unroll
    for (int i = 0; i < 4; ++i) {
        const int idx = i * 256 + t;
        const int e  = idx >> 4;
        const int kq = idx & 15;
        const int eid = eids_l[e];
        float4 v = make_float4(0.f, 0.f, 0.f, 0.f);
        if (eid >= 0) v = *(const float4*)(edge_scalars + (long long)eid * FCn + kq * 4);
        XT[(kq * 4 + 0) * LDP + e] = v.x;
        XT[(kq * 4 + 1) * LDP + e] = v.y;
        XT[(kq * 4 + 2) * LDP + e] = v.z;
        XT[(kq * 4 + 3) * LDP + e] = v.w;
    }
    for (int i = t; i < TEB * 9; i += 256) {
        const int e = i / 9, j = i - e * 9;
        const int eid = eids_l[e];
        Ea[e * ABP + j] = (eid >= 0) ? edge_attr[(long long)eid * 9 + j] : 0.f;
    }
    __syncthreads();

    // ---- GEMM1: H = X @ W1 + b1 (64e x 64c), per-thread 4x4
    {
        const int eg = t >> 4, cg = t & 15;
        float a[4][4];
        #pragma unroll
        for (int i = 0; i < 4; ++i)
            #pragma unroll
            for (int j = 0; j < 4; ++j) a[i][j] = 0.f;
        for (int k = 0; k < FCn; ++k) {
            const float4 xv = *(const float4*)&XT[k * LDP + eg * 4];
            const float4 wv = *(const float4*)&rad_w1[k * FCn + cg * 4];
            const float xe[4] = {xv.x, xv.y, xv.z, xv.w};
            const float wc[4] = {wv.x, wv.y, wv.z, wv.w};
            #pragma unroll
            for (int i = 0; i < 4; ++i)
                #pragma unroll
                for (int j = 0; j < 4; ++j)
                    a[i][j] += xe[i] * wc[j];
        }
        const float4 bv = *(const float4*)&rad_b1[cg * 4];
        const float bb[4] = {bv.x, bv.y, bv.z, bv.w};
        #pragma unroll
        for (int i = 0; i < 4; ++i) {
            float4 o;
            o.x = a[i][0] + bb[0]; o.y = a[i][1] + bb[1];
            o.z = a[i][2] + bb[2]; o.w = a[i][3] + bb[3];
            *(float4*)&Hb[(eg * 4 + i) * LDP + cg * 4] = o;
        }
    }
    __syncthreads();

    // ---- LayerNorm + silu: 4 threads per edge, shfl reduce; write He[e][k] (alias XT)
    {
        const int e = t >> 2, q4 = t & 3;
        const float* hrow = &Hb[e * LDP + q4 * 16];
        float4 r[4];
        float s1 = 0.f, s2 = 0.f;
        #pragma unroll
        for (int i = 0; i < 4; ++i) {
            r[i] = *(const float4*)(hrow + i * 4);
            s1 += r[i].x + r[i].y + r[i].z + r[i].w;
            s2 += r[i].x * r[i].x + r[i].y * r[i].y + r[i].z * r[i].z + r[i].w * r[i].w;
        }
        s1 += __shfl_xor(s1, 1); s1 += __shfl_xor(s1, 2);
        s2 += __shfl_xor(s2, 1); s2 += __shfl_xor(s2, 2);
        const float mu  = s1 * (1.f / 64.f);
        const float var = s2 * (1.f / 64.f) - mu * mu;
        const float rs  = rsqrtf(var + 1e-5f);
        #pragma unroll
        for (int i = 0; i < 4; ++i) {
            const int c0 = q4 * 16 + i * 4;
            const float4 gm = *(const float4*)&rad_gamma[c0];
            const float4 bt = *(const float4*)&rad_beta[c0];
            float4 o;
            o.x = silu_f((r[i].x - mu) * rs * gm.x + bt.x);
            o.y = silu_f((r[i].y - mu) * rs * gm.y + bt.y);
            o.z = silu_f((r[i].z - mu) * rs * gm.z + bt.z);
            o.w = silu_f((r[i].w - mu) * rs * gm.w + bt.w);
            *(float4*)&XT[e * LDP + c0] = o;   // He row e
        }
    }
    __syncthreads();

    // ---- segment accumulation of G and A (registers), flush on dst change
    const int k  = t & 63;
    const int jg = t >> 6;            // 0..3
    const int j0 = jg, j1 = jg + 4;   // jg==0 additionally owns j=8
    const bool has2 = (jg == 0);
    float g0 = 0.f, g1 = 0.f, g2 = 0.f;
    float a0 = 0.f, a1 = 0.f, a2 = 0.f;
    int curn = dst_l[0];
    for (int e = 0; e < TEB; ++e) {
        const int nid = dst_l[e];
        if (nid != curn) {
            if (curn >= 0) {
                float* gp = G + (long long)curn * GJK;
                atomicAdd(gp + j0 * 64 + k, g0);
                atomicAdd(gp + j1 * 64 + k, g1);
                if (has2) atomicAdd(gp + 8 * 64 + k, g2);
                if (k == 0) {
                    float* ap = Ab + (long long)curn * ABP;
                    atomicAdd(ap + j0, a0);
                    atomicAdd(ap + j1, a1);
                    if (has2) atomicAdd(ap + 8, a2);
                }
            }
            g0 = g1 = g2 = 0.f; a0 = a1 = a2 = 0.f;
            curn = nid;
        }
        if (nid < 0) break;   // sorted: invalid only at tail
        const float h  = XT[e * LDP + k];       // He[e][k], conflict-free stride
        const float e0 = Ea[e * ABP + j0];      // wave-broadcast
        const float e1 = Ea[e * ABP + j1];
        g0 = fmaf(e0, h, g0); a0 += e0;
        g1 = fmaf(e1, h, g1); a1 += e1;
        if (has2) {
            const float e2 = Ea[e * ABP + 8];
            g2 = fmaf(e2, h, g2); a2 += e2;
        }
    }
    if (curn >= 0) {
        float* gp = G + (long long)curn * GJK;
        atomicAdd(gp + j0 * 64 + k, g0);
        atomicAdd(gp + j1 * 64 + k, g1);
        if (has2) atomicAdd(gp + 8 * 64 + k, g2);
        if (k == 0) {
            float* ap = Ab + (long long)curn * ABP;
            atomicAdd(ap + j0, a0);
            atomicAdd(ap + j1, a1);
            if (has2) atomicAdd(ap + 8, a2);
        }
    }
}

// ---------------- pass 2: out[n,c] = G[n,j(c),:]·MT[t(c),:] + Ab[n,j(c)]*cvec[t(c)]
//                                     + (c<128 ? deg*b0s[c] : 0)
// MT staged once per block in LDS; 4 nodes per iteration amortize LDS reads.
__global__ __launch_bounds__(512, 2) void project_kernel(
    const float* __restrict__ G, const float* __restrict__ Ab,
    const int*   __restrict__ off,
    const float* __restrict__ MT, const float* __restrict__ cvec,
    const float* __restrict__ b0s,
    float* __restrict__ out, int Nn)
{
    __shared__ float MTl[224 * LDP];      // 60,928 B
    __shared__ float Gs[4 * 9 * 72];      // 10,368 B
    __shared__ float sA[4 * ABP];
    __shared__ float cv[224];
    __shared__ float bs[128];
    __shared__ int   dg[4];
    const int t = threadIdx.x;

    for (int i = t; i < 224 * FCn; i += 512) {
        const int c = i >> 6, kk = i & 63;
        MTl[c * LDP + kk] = MT[i];
    }
    if (t < 224) cv[t] = cvec[t];
    if (t < 128) bs[t] = b0s[t];

    // out col t -> (T col, edge_attr col)
    int tIdx = 0, jIdx = 0;
    if (t < 128)      { tIdx = t; jIdx = 0; }
    else if (t < 320) { const int idx = t - 128; tIdx = 128 + idx / 3; jIdx = 1 + idx % 3; }
    else if (t < 480) { const int idx = t - 320; tIdx = 192 + idx / 5; jIdx = 4 + idx % 5; }

    for (int n0 = blockIdx.x * 4; n0 < Nn; n0 += gridDim.x * 4) {
        for (int i = t; i < 4 * GJK; i += 512) {
            const int nb = i / GJK, r = i - nb * GJK;
            const int n = n0 + nb;
            Gs[nb * 648 + (r >> 6) * 72 + (r & 63)] = (n < Nn) ? G[(long long)n * GJK + r] : 0.f;
        }
        if (t < 4 * ABP) {
            const int nb = t / ABP, j = t - nb * ABP;
            const int n = n0 + nb;
            sA[t] = (n < Nn) ? Ab[(long long)n * ABP + j] : 0.f;
        }
        if (t < 4) {
            const int n = n0 + t;
            dg[t] = (n < Nn) ? off[n + 1] - off[n] : 0;
        }
        __syncthreads();
        if (t < 480) {
            const float cvv = cv[tIdx];
            const float bsv = (t < 128) ? bs[t] : 0.f;
            float acc0 = sA[0 * ABP + jIdx] * cvv + (float)dg[0] * bsv;
            float acc1 = sA[1 * ABP + jIdx] * cvv + (float)dg[1] * bsv;
            float acc2 = sA[2 * ABP + jIdx] * cvv + (float)dg[2] * bsv;
            float acc3 = sA[3 * ABP + jIdx] * cvv + (float)dg[3] * bsv;
            const float* mrow = &MTl[tIdx * LDP];
            const float* g0p = &Gs[0 * 648 + jIdx * 72];
            const float* g1p = &Gs[1 * 648 + jIdx * 72];
            const float* g2p = &Gs[2 * 648 + jIdx * 72];
            const float* g3p = &Gs[3 * 648 + jIdx * 72];
            #pragma unroll
            for (int q = 0; q < 16; ++q) {
                const float4 m  = *(const float4*)(mrow + q * 4);
                const float4 ga = *(const float4*)(g0p + q * 4);
                const float4 gb = *(const float4*)(g1p + q * 4);
                const float4 gc = *(const float4*)(g2p + q * 4);
                const float4 gd = *(const float4*)(g3p + q * 4);
                acc0 += m.x * ga.x + m.y * ga.y + m.z * ga.z + m.w * ga.w;
                acc1 += m.x * gb.x + m.y * gb.y + m.z * gb.z + m.w * gb.w;
                acc2 += m.x * gc.x + m.y * gc.y + m.z * gc.z + m.w * gc.w;
                acc3 += m.x * gd.x + m.y * gd.y + m.z * gd.z + m.w * gd.w;
            }
            const long long ob = (long long)n0 * 480 + t;
            if (n0 + 0 < Nn) out[ob           ] = acc0;
            if (n0 + 1 < Nn) out[ob + 480     ] = acc1;
            if (n0 + 2 < Nn) out[ob + 2 * 480 ] = acc2;
            if (n0 + 3 < Nn) out[ob + 3 * 480 ] = acc3;
        }
        __syncthreads();
    }
}

extern "C" void kernel_launch(void* const* d_in, const int* in_sizes, int n_in,
                              void* d_out, int out_size, void* d_ws, size_t ws_size,
                              hipStream_t stream)
{
    const float* edge_attr    = (const float*)d_in[1];
    const float* edge_scalars = (const float*)d_in[2];
    const int*   edge_dst     = (const int*)d_in[4];
    const float* exp_w     = (const float*)d_in[6];
    const float* exp_b     = (const float*)d_in[7];
    const float* rad_w1    = (const float*)d_in[8];
    const float* rad_b1    = (const float*)d_in[9];
    const float* rad_gamma = (const float*)d_in[10];
    const float* rad_beta  = (const float*)d_in[11];
    const float* rad_w2    = (const float*)d_in[12];
    const float* rad_b2    = (const float*)d_in[13];
    const float* proj_w0   = (const float*)d_in[14];
    const float* proj_b0   = (const float*)d_in[15];
    const float* proj_w1   = (const float*)d_in[16];
    const float* proj_w2   = (const float*)d_in[17];
    float* out = (float*)d_out;
    const int E = in_sizes[4];
    const int Nn = out_size / 480;

    // ws layout: MT, cvec, b0s, off, cnt, cur, eids, G, Ab
    float* MT   = (float*)d_ws;                 // 224*64
    float* cvec = MT + 224 * FCn;               // 256
    float* b0s  = cvec + 256;                   // 128
    int* off  = (int*)(b0s + 128);              // Nn+1
    int* cnt  = off + (Nn + 1);                 // Nn
    int* cur  = cnt + Nn;                       // Nn
    int* eids = cur + Nn;                       // E
    size_t gOff = (size_t)((char*)(eids + E) - (char*)d_ws);
    gOff = (gOff + 255) & ~(size_t)255;
    float* G  = (float*)((char*)d_ws + gOff);   // Nn x 576
    float* Ab = G + (size_t)Nn * GJK;           // Nn x 12 (contiguous with G)

    precomp_kernel<<<FCn + 1, 256, 0, stream>>>(exp_w, exp_b, rad_w2, rad_b2,
                                                proj_w0, proj_b0, proj_w1, proj_w2,
                                                MT, cvec, b0s);
    hipMemsetAsync(cnt, 0, (size_t)Nn * sizeof(int), stream);
    hipMemsetAsync(G, 0, (size_t)Nn * (GJK + ABP) * sizeof(float), stream);
    hist_kernel<<<512, 256, 0, stream>>>(edge_dst, cnt, E);
    scan_kernel<<<1, 256, 0, stream>>>(cnt, off, cur, Nn, E);
    scatter_kernel<<<512, 256, 0, stream>>>(edge_dst, cur, eids, E);

    const int blocks = (E + TEB - 1) / TEB;
    accumG_kernel<<<blocks, 256, 0, stream>>>(edge_attr, edge_scalars, eids, edge_dst,
                                              rad_w1, rad_b1, rad_gamma, rad_beta,
                                              G, Ab, E);
    project_kernel<<<512, 512, 0, stream>>>(G, Ab, off, MT, cvec, b0s, out, Nn);
}